// Round 17
// baseline (130.093 us; speedup 1.0000x reference)
//
#include <hip/hip_runtime.h>
#include <hip/hip_bf16.h>

typedef __bf16 bf16_t;
typedef __bf16 bf16x2 __attribute__((ext_vector_type(2)));
typedef __bf16 bf16x4 __attribute__((ext_vector_type(4)));
typedef __bf16 bf16x8 __attribute__((ext_vector_type(8)));
typedef float  f32x4  __attribute__((ext_vector_type(4)));

#define GLDS16(gp, lp) __builtin_amdgcn_global_load_lds( \
    (const __attribute__((address_space(1))) void*)(gp), \
    (__attribute__((address_space(3))) void*)(lp), 16, 0, 0)

#define MFMA16(a, b, c) __builtin_amdgcn_mfma_f32_16x16x32_bf16((a), (b), (c), 0, 0, 0)

static constexpr int kB = 2, kS = 2048, kD = 1024, kH = 16, kL = 64;
static constexpr int kM = kB * kS;       // 4096 rows
static constexpr int kNqkv = 3 * kD;     // 3072
static constexpr int kBH = kB * kH;      // 32

// ---------------------------------------------------------------------------
// K1: fused prep — blockIdx.x ranges: [0,4096) cast_x; [4096,8192) wtrans;
// [8192,8448) rope_table.
// ---------------------------------------------------------------------------
__global__ __launch_bounds__(256)
void prep_kernel(const float* __restrict__ x, bf16_t* __restrict__ xb,
                 const float* __restrict__ Wq, const float* __restrict__ Wk,
                 const float* __restrict__ Wv, const float* __restrict__ Wo,
                 bf16_t* __restrict__ Wqkv, bf16_t* __restrict__ WoT,
                 float* __restrict__ cosT, float* __restrict__ sinT) {
    const int bid = blockIdx.x;
    const int tid = threadIdx.x;
    if (bid < 4096) {
        int i = bid * 256 + tid;
        float4 v = ((const float4*)x)[i];
        bf16x4 o;
        o[0] = (bf16_t)v.x; o[1] = (bf16_t)v.y; o[2] = (bf16_t)v.z; o[3] = (bf16_t)v.w;
        ((bf16x4*)xb)[i] = o;
    } else if (bid < 8192) {
        __shared__ float t[32 * 33];
        const int wid4 = bid - 4096;
        const int z = wid4 >> 10;
        const int rem = wid4 & 1023;
        const int k0 = (rem & 31) * 32, n0 = (rem >> 5) * 32;
        const float* W = (z == 0) ? Wq : (z == 1) ? Wk : (z == 2) ? Wv : Wo;
        bf16_t* Wt = (z < 3) ? (Wqkv + (size_t)z * 1024 * 1024) : WoT;
#pragma unroll
        for (int i = 0; i < 4; ++i) {
            int idx = i * 256 + tid;
            int r = idx >> 5, c = idx & 31;
            t[r * 33 + c] = W[(size_t)(k0 + r) * 1024 + n0 + c];
        }
        __syncthreads();
#pragma unroll
        for (int i = 0; i < 4; ++i) {
            int idx = i * 256 + tid;
            int r = idx >> 5, c = idx & 31;
            Wt[(size_t)(n0 + r) * 1024 + k0 + c] = (bf16_t)t[c * 33 + r];
        }
    } else {
        int i = (bid - 8192) * 256 + tid;
        int s = i >> 5, j = i & 31;
        double inv = pow(10000.0, -2.0 * (double)j / 64.0);
        double ang = (double)s * inv;
        cosT[i] = (float)cos(ang);
        sinT[i] = (float)sin(ang);
    }
}

// ---------------------------------------------------------------------------
// K2/K8: bf16 GEMM (r16 form — dbuf, neutral but verified)
// ---------------------------------------------------------------------------
template <int MODE>
__global__ __launch_bounds__(256, 4)
void gemm_bf16(const bf16_t* __restrict__ A, const bf16_t* __restrict__ Bt,
               void* __restrict__ Cout,
               const float* __restrict__ b0, const float* __restrict__ b1,
               const float* __restrict__ b2, int Ndim, int Kdim) {
    __shared__ __align__(16) bf16_t Alds[2][128 * 32];
    __shared__ __align__(16) bf16_t Blds[2][128 * 32];
    const int tid = threadIdx.x;
    const int lane = tid & 63;
    const int wid = tid >> 6;
    const int lo = lane & 15, hi = lane >> 4;
    const int bm = blockIdx.x, bn = blockIdx.y;
    const int wr = wid >> 1, wc = wid & 1;

    const int rowS = (wid * 2) * 16 + (lane >> 2);
    const int colE = (lane & 3) * 8;
    const bf16_t* gA0 = A + (size_t)(bm * 128 + rowS) * Kdim + colE;
    const bf16_t* gA1 = gA0 + (size_t)16 * Kdim;
    const bf16_t* gB0 = Bt + (size_t)(bn * 128 + rowS) * Kdim + colE;
    const bf16_t* gB1 = gB0 + (size_t)16 * Kdim;

    f32x4 acc[4][4];
#pragma unroll
    for (int m = 0; m < 4; ++m)
#pragma unroll
        for (int n = 0; n < 4; ++n) acc[m][n] = (f32x4){0.f, 0.f, 0.f, 0.f};

    auto stage = [&](int buf, int kt) {
        const int k0 = kt * 32;
        GLDS16(gA0 + k0, &Alds[buf][(wid * 2) * 512]);
        GLDS16(gA1 + k0, &Alds[buf][(wid * 2 + 1) * 512]);
        GLDS16(gB0 + k0, &Blds[buf][(wid * 2) * 512]);
        GLDS16(gB1 + k0, &Blds[buf][(wid * 2 + 1) * 512]);
    };

    const int nk = Kdim >> 5;
    stage(0, 0);
    int cur = 0;
    for (int kt = 0; kt < nk; ++kt) {
        __syncthreads();
        if (kt + 1 < nk) stage(cur ^ 1, kt + 1);
        bf16x8 aF[4], bF[4];
#pragma unroll
        for (int m = 0; m < 4; ++m)
            aF[m] = *(const bf16x8*)&Alds[cur][(wr * 64 + m * 16 + lo) * 32 + hi * 8];
#pragma unroll
        for (int n = 0; n < 4; ++n)
            bF[n] = *(const bf16x8*)&Blds[cur][(wc * 64 + n * 16 + lo) * 32 + hi * 8];
#pragma unroll
        for (int m = 0; m < 4; ++m)
#pragma unroll
            for (int n = 0; n < 4; ++n)
                acc[m][n] = MFMA16(aF[m], bF[n], acc[m][n]);
        cur ^= 1;
    }

    const int rbase = bm * 128 + wr * 64 + hi * 4;
    const int cbase = bn * 128 + wc * 64 + lo;
    if (MODE == 0) {
        bf16_t* C = (bf16_t*)Cout;
#pragma unroll
        for (int m = 0; m < 4; ++m)
#pragma unroll
            for (int n = 0; n < 4; ++n) {
                const int col = cbase + n * 16;
                const float bias = (col < 1024) ? b0[col]
                                 : (col < 2048) ? b1[col - 1024] : b2[col - 2048];
#pragma unroll
                for (int r = 0; r < 4; ++r) {
                    const int row = rbase + m * 16 + r;
                    C[(size_t)row * Ndim + col] = (bf16_t)(acc[m][n][r] + bias);
                }
            }
    } else {
        float* C = (float*)Cout;
#pragma unroll
        for (int m = 0; m < 4; ++m)
#pragma unroll
            for (int n = 0; n < 4; ++n) {
                const int col = cbase + n * 16;
                const float bias = b0[col];
#pragma unroll
                for (int r = 0; r < 4; ++r) {
                    const int row = rbase + m * 16 + r;
                    C[(size_t)row * Ndim + col] = acc[m][n][r] + bias;
                }
            }
    }
}

// ---------------------------------------------------------------------------
// K3: fused RoPE(Q,K) + V-transpose (r15-verified)
// ---------------------------------------------------------------------------
__global__ __launch_bounds__(256)
void qkvprep_kernel(const bf16_t* __restrict__ qkv,
                    const float* __restrict__ cosT,
                    const float* __restrict__ sinT,
                    bf16_t* __restrict__ Qr, bf16_t* __restrict__ Kr,
                    bf16_t* __restrict__ VT) {
    const int st = blockIdx.x, bh = blockIdx.y;
    const int b = bh >> 4, h = bh & 15;
    const int tid = threadIdx.x;
    {
        const int r = tid >> 2;
        const int part = tid & 3;
        const int s = st * 64 + r;
        const int bs = b * kS + s;
        const bf16_t* qp = qkv + (size_t)bs * kNqkv + h * 64 + part * 16;
        const bf16_t* kp = qp + 1024;
        const size_t outoff = ((size_t)(b * kH + h) * kS + s) * 64;
        bf16_t* qo = Qr + outoff;
        char*   kob = (char*)(Kr + outoff);
        const float* cr = cosT + s * 32 + part * 8;
        const float* sr = sinT + s * 32 + part * 8;
        const float kScale = 0.125f * 1.44269504f;

        bf16x8 q0 = *(const bf16x8*)qp;
        bf16x8 q1 = *(const bf16x8*)(qp + 8);
        bf16x8 k0 = *(const bf16x8*)kp;
        bf16x8 k1 = *(const bf16x8*)(kp + 8);
        bf16x8 qlo, qhi, klo, khi;
#pragma unroll
        for (int j = 0; j < 8; ++j) {
            const float cv = cr[j];
            const float sv = sr[j];
            float qa, qb2, ka, kb2;
            if (j < 4) {
                qa = (float)q0[2 * j];     qb2 = (float)q0[2 * j + 1];
                ka = (float)k0[2 * j];     kb2 = (float)k0[2 * j + 1];
            } else {
                qa = (float)q1[2 * j - 8]; qb2 = (float)q1[2 * j - 7];
                ka = (float)k1[2 * j - 8]; kb2 = (float)k1[2 * j - 7];
            }
            qlo[j] = (bf16_t)((qa * cv - qb2 * sv) * kScale);
            qhi[j] = (bf16_t)((qa * sv + qb2 * cv) * kScale);
            klo[j] = (bf16_t)(ka * cv - kb2 * sv);
            khi[j] = (bf16_t)(ka * sv + kb2 * cv);
        }
        *(bf16x8*)(qo + part * 8)      = qlo;
        *(bf16x8*)(qo + 32 + part * 8) = qhi;
        const int sw = s & 7;
        *(bf16x8*)(kob + (((part)     ^ sw) << 4)) = klo;
        *(bf16x8*)(kob + (((part + 4) ^ sw) << 4)) = khi;
    }
    {
        __shared__ __align__(16) bf16_t t[64 * 72];
        const int r = tid >> 2, g = tid & 3;
        const bf16_t* src = qkv + ((size_t)(b * kS + st * 64 + r)) * kNqkv + 2048 + h * 64 + g * 16;
        bf16x8 v0 = *(const bf16x8*)src;
        bf16x8 v1 = *(const bf16x8*)(src + 8);
        *(bf16x8*)&t[r * 72 + g * 16] = v0;
        *(bf16x8*)&t[r * 72 + g * 16 + 8] = v1;
        __syncthreads();
        bf16x8 o0, o1;
#pragma unroll
        for (int j = 0; j < 8; ++j) {
            o0[j] = t[(g * 16 + j) * 72 + r];
            o1[j] = t[(g * 16 + 8 + j) * 72 + r];
        }
        char* dstb = (char*)(VT + ((size_t)bh * 64 + r) * kS) + st * 128;
        const int sw = r & 7;
        *(bf16x8*)(dstb + (((g * 2)     ^ sw) << 4)) = o0;
        *(bf16x8*)(dstb + (((g * 2 + 1) ^ sw) << 4)) = o1;
    }
}

// ---------------------------------------------------------------------------
// K5: causal flash attention v15 — r12 compute, SINGLE KV buffer (24KB LDS)
// for 6 blocks/CU. Loop: stage(t) -> barrier -> compute -> barrier.
// Cross-block TLP (24 waves/CU) hides the serialized stage.
// ---------------------------------------------------------------------------
__global__ __launch_bounds__(256, 6)
void attn_kernel(const bf16_t* __restrict__ Qr, const bf16_t* __restrict__ Kr,
                 const bf16_t* __restrict__ VT, bf16_t* __restrict__ attended) {
    __shared__ __align__(16) bf16_t Klds[64 * 64];
    __shared__ __align__(16) bf16_t Vlds[64 * 64];
    __shared__ __align__(16) bf16_t Plds[4][16 * 64];
    const int bh = blockIdx.x;
    const int y = blockIdx.y;
    const int qt = (y < 8) ? (31 - y) : (y < 16) ? (y + 8)
                 : (y < 24) ? (31 - y) : (y - 24);
    const int tid = threadIdx.x;
    const int lane = tid & 63, wid = tid >> 6;
    const int lo = lane & 15, hi = lane >> 4;
    const int q0 = qt * 64 + wid * 16;

    const char* Kg = (const char*)(Kr + (size_t)bh * kS * 64);
    const char* Vg = (const char*)(VT + (size_t)bh * 64 * kS);
    const bf16_t* Q = Qr + (size_t)bh * kS * 64;

    const bf16x8 aQ0 = *(const bf16x8*)&Q[(size_t)(q0 + lo) * 64 + hi * 8];
    const bf16x8 aQ1 = *(const bf16x8*)&Q[(size_t)(q0 + lo) * 64 + 32 + hi * 8];

    char* Pb = (char*)&Plds[wid][0];
    const int psw = (lo & 7) << 4;

    f32x4 O[4];
#pragma unroll
    for (int dt = 0; dt < 4; ++dt) O[dt] = (f32x4){0.f, 0.f, 0.f, 0.f};
    float m_run = -1e30f, l_run = 0.f;

    auto stage = [&](int t) {
        char* Kl = (char*)&Klds[0];
        char* Vl = (char*)&Vlds[0];
        const size_t kb = (size_t)t * 128 * 64;
        const int vcol = t * 128;
#pragma unroll
        for (int j = 0; j < 2; ++j) {
            const int seg = wid * 2 + j;
            GLDS16(Kg + kb + seg * 1024 + lane * 16, Kl + seg * 1024);
            const int row = seg * 8 + (lane >> 3);
            GLDS16(Vg + (size_t)row * (kS * 2) + vcol + (lane & 7) * 16, Vl + seg * 1024);
        }
    };

    const int ntiles = qt + 1;
    for (int t = 0; t < ntiles; ++t) {
        stage(t);
        __syncthreads();                       // drain staging, data visible
        const char* Kb = (const char*)&Klds[0];
        const char* Vb = (const char*)&Vlds[0];
        const int kv0 = t * 64;
        const bool edge = (t == qt);

        f32x4 s[4];
#pragma unroll
        for (int ct = 0; ct < 4; ++ct) s[ct] = (f32x4){0.f, 0.f, 0.f, 0.f};
        __builtin_amdgcn_s_setprio(1);
#pragma unroll
        for (int ct = 0; ct < 4; ++ct) {
            const int rr = ct * 16 + lo;
            const bf16x8 bK0 = *(const bf16x8*)(Kb + rr * 128 + (((hi)     ^ (rr & 7)) << 4));
            const bf16x8 bK1 = *(const bf16x8*)(Kb + rr * 128 + (((hi + 4) ^ (rr & 7)) << 4));
            s[ct] = MFMA16(bK0, aQ0, s[ct]);
            s[ct] = MFMA16(bK1, aQ1, s[ct]);
        }
        __builtin_amdgcn_s_setprio(0);

        if (edge) {
            const int qg = q0 + lo;
#pragma unroll
            for (int ct = 0; ct < 4; ++ct)
#pragma unroll
                for (int r = 0; r < 4; ++r)
                    if (kv0 + ct * 16 + hi * 4 + r > qg) s[ct][r] = -1e30f;
        }
        float pmax = -1e30f;
#pragma unroll
        for (int ct = 0; ct < 4; ++ct)
#pragma unroll
            for (int r = 0; r < 4; ++r) pmax = fmaxf(pmax, s[ct][r]);
        pmax = fmaxf(pmax, __shfl_xor(pmax, 16, 64));
        pmax = fmaxf(pmax, __shfl_xor(pmax, 32, 64));
        if (!__all(pmax - m_run <= 8.0f)) {
            const float mn = fmaxf(m_run, pmax);
            const float alpha = exp2f(m_run - mn);
            m_run = mn;
            l_run *= alpha;
            float av[4];
#pragma unroll
            for (int r = 0; r < 4; ++r) av[r] = __shfl(alpha, hi * 4 + r, 64);
#pragma unroll
            for (int dt = 0; dt < 4; ++dt)
#pragma unroll
                for (int r = 0; r < 4; ++r) O[dt][r] *= av[r];
        }
        float psum = 0.f;
#pragma unroll
        for (int ct = 0; ct < 4; ++ct)
#pragma unroll
            for (int r = 0; r < 4; ++r) {
                const float e = exp2f(s[ct][r] - m_run);
                s[ct][r] = e;
                psum += e;
            }
        psum += __shfl_xor(psum, 16, 64);
        psum += __shfl_xor(psum, 32, 64);
        l_run += psum;
#pragma unroll
        for (int ct = 0; ct < 4; ++ct)
#pragma unroll
            for (int rp = 0; rp < 2; ++rp) {
                bf16x2 v;
                v[0] = (bf16_t)s[ct][2 * rp];
                v[1] = (bf16_t)s[ct][2 * rp + 1];
                *(bf16x2*)(Pb + ((lo * 128 + (ct * 16 + hi * 4 + 2 * rp) * 2) ^ psw)) = v;
            }
        const bf16x8 aP0 = *(const bf16x8*)(Pb + ((lo * 128 + hi * 16) ^ psw));
        const bf16x8 aP1 = *(const bf16x8*)(Pb + ((lo * 128 + 64 + hi * 16) ^ psw));

        __builtin_amdgcn_s_setprio(1);
#pragma unroll
        for (int dt = 0; dt < 4; ++dt) {
            const int rr = dt * 16 + lo;
            const bf16x8 bV0 = *(const bf16x8*)(Vb + rr * 128 + (((hi)     ^ (rr & 7)) << 4));
            const bf16x8 bV1 = *(const bf16x8*)(Vb + rr * 128 + (((hi + 4) ^ (rr & 7)) << 4));
            O[dt] = MFMA16(aP0, bV0, O[dt]);
            O[dt] = MFMA16(aP1, bV1, O[dt]);
        }
        __builtin_amdgcn_s_setprio(0);
        __syncthreads();                       // all reads done before next stage
    }

    const int b = bh >> 4, h = bh & 15;
    float li[4];
#pragma unroll
    for (int r = 0; r < 4; ++r) li[r] = 1.0f / __shfl(l_run, hi * 4 + r, 64);
#pragma unroll
    for (int dt = 0; dt < 4; ++dt)
#pragma unroll
        for (int r = 0; r < 4; ++r) {
            const int row = q0 + hi * 4 + r;
            attended[((size_t)(b * kS + row)) * kD + h * 64 + dt * 16 + lo] =
                (bf16_t)(O[dt][r] * li[r]);
        }
}

// ---------------------------------------------------------------------------
extern "C" void kernel_launch(void* const* d_in, const int* in_sizes, int n_in,
                              void* d_out, int out_size, void* d_ws, size_t ws_size,
                              hipStream_t stream) {
    const float* x  = (const float*)d_in[0];
    const float* Wq = (const float*)d_in[1];
    const float* bq = (const float*)d_in[2];
    const float* Wk = (const float*)d_in[3];
    const float* bk = (const float*)d_in[4];
    const float* Wv = (const float*)d_in[5];
    const float* bv = (const float*)d_in[6];
    const float* Wo = (const float*)d_in[7];
    const float* bo = (const float*)d_in[8];
    float* out = (float*)d_out;

    char* ws = (char*)d_ws;
    size_t off = 0;
    auto carve = [&](size_t bytes) -> char* {
        char* p = ws + off;
        off += (bytes + 255) & ~(size_t)255;
        return p;
    };
    bf16_t* xb    = (bf16_t*)carve((size_t)kM * kD * 2);
    bf16_t* WqkvT = (bf16_t*)carve((size_t)kNqkv * kD * 2);
    bf16_t* WoT   = (bf16_t*)carve((size_t)kD * kD * 2);
    float*  cosT  = (float*)carve((size_t)kS * 32 * 4);
    float*  sinT  = (float*)carve((size_t)kS * 32 * 4);
    bf16_t* qkv   = (bf16_t*)carve((size_t)kM * kNqkv * 2);
    bf16_t* Qr    = (bf16_t*)carve((size_t)kBH * kS * 64 * 2);
    bf16_t* Kr    = (bf16_t*)carve((size_t)kBH * kS * 64 * 2);
    bf16_t* VT    = (bf16_t*)carve((size_t)kBH * kS * 64 * 2);
    bf16_t* att   = (bf16_t*)carve((size_t)kM * kD * 2);

    prep_kernel<<<8448, 256, 0, stream>>>(x, xb, Wq, Wk, Wv, Wo, WqkvT, WoT, cosT, sinT);

    gemm_bf16<0><<<dim3(kM / 128, kNqkv / 128), 256, 0, stream>>>(
        xb, WqkvT, qkv, bq, bk, bv, kNqkv, kD);

    qkvprep_kernel<<<dim3(kS / 64, kBH), 256, 0, stream>>>(qkv, cosT, sinT, Qr, Kr, VT);

    attn_kernel<<<dim3(kBH, 32), 256, 0, stream>>>(Qr, Kr, VT, att);

    gemm_bf16<1><<<dim3(kM / 128, kD / 128), 256, 0, stream>>>(
        att, WoT, out, bo, nullptr, nullptr, kD, kD);
}

// Round 18
// 125.772 us; speedup vs baseline: 1.0344x; 1.0344x over previous
//
#include <hip/hip_runtime.h>
#include <hip/hip_bf16.h>

typedef __bf16 bf16_t;
typedef __bf16 bf16x2 __attribute__((ext_vector_type(2)));
typedef __bf16 bf16x4 __attribute__((ext_vector_type(4)));
typedef __bf16 bf16x8 __attribute__((ext_vector_type(8)));
typedef float  f32x4  __attribute__((ext_vector_type(4)));

#define GLDS16(gp, lp) __builtin_amdgcn_global_load_lds( \
    (const __attribute__((address_space(1))) void*)(gp), \
    (__attribute__((address_space(3))) void*)(lp), 16, 0, 0)

#define MFMA16(a, b, c) __builtin_amdgcn_mfma_f32_16x16x32_bf16((a), (b), (c), 0, 0, 0)

static constexpr int kB = 2, kS = 2048, kD = 1024, kH = 16, kL = 64;
static constexpr int kM = kB * kS;       // 4096 rows
static constexpr int kNqkv = 3 * kD;     // 3072
static constexpr int kBH = kB * kH;      // 32

// ---------------------------------------------------------------------------
// K1: fused prep — blockIdx.x ranges: [0,4096) cast_x; [4096,8192) wtrans;
// [8192,8448) rope_table.
// ---------------------------------------------------------------------------
__global__ __launch_bounds__(256)
void prep_kernel(const float* __restrict__ x, bf16_t* __restrict__ xb,
                 const float* __restrict__ Wq, const float* __restrict__ Wk,
                 const float* __restrict__ Wv, const float* __restrict__ Wo,
                 bf16_t* __restrict__ Wqkv, bf16_t* __restrict__ WoT,
                 float* __restrict__ cosT, float* __restrict__ sinT) {
    const int bid = blockIdx.x;
    const int tid = threadIdx.x;
    if (bid < 4096) {
        int i = bid * 256 + tid;
        float4 v = ((const float4*)x)[i];
        bf16x4 o;
        o[0] = (bf16_t)v.x; o[1] = (bf16_t)v.y; o[2] = (bf16_t)v.z; o[3] = (bf16_t)v.w;
        ((bf16x4*)xb)[i] = o;
    } else if (bid < 8192) {
        __shared__ float t[32 * 33];
        const int wid4 = bid - 4096;
        const int z = wid4 >> 10;
        const int rem = wid4 & 1023;
        const int k0 = (rem & 31) * 32, n0 = (rem >> 5) * 32;
        const float* W = (z == 0) ? Wq : (z == 1) ? Wk : (z == 2) ? Wv : Wo;
        bf16_t* Wt = (z < 3) ? (Wqkv + (size_t)z * 1024 * 1024) : WoT;
#pragma unroll
        for (int i = 0; i < 4; ++i) {
            int idx = i * 256 + tid;
            int r = idx >> 5, c = idx & 31;
            t[r * 33 + c] = W[(size_t)(k0 + r) * 1024 + n0 + c];
        }
        __syncthreads();
#pragma unroll
        for (int i = 0; i < 4; ++i) {
            int idx = i * 256 + tid;
            int r = idx >> 5, c = idx & 31;
            Wt[(size_t)(n0 + r) * 1024 + k0 + c] = (bf16_t)t[c * 33 + r];
        }
    } else {
        int i = (bid - 8192) * 256 + tid;
        int s = i >> 5, j = i & 31;
        double inv = pow(10000.0, -2.0 * (double)j / 64.0);
        double ang = (double)s * inv;
        cosT[i] = (float)cos(ang);
        sinT[i] = (float)sin(ang);
    }
}

// ---------------------------------------------------------------------------
// K2/K8: bf16 GEMM (m97 structure, r15-verified)
// ---------------------------------------------------------------------------
template <int MODE>
__global__ __launch_bounds__(256, 2)
void gemm_bf16(const bf16_t* __restrict__ A, const bf16_t* __restrict__ Bt,
               void* __restrict__ Cout,
               const float* __restrict__ b0, const float* __restrict__ b1,
               const float* __restrict__ b2, int Ndim, int Kdim) {
    __shared__ __align__(16) bf16_t Alds[128 * 32];
    __shared__ __align__(16) bf16_t Blds[128 * 32];
    const int tid = threadIdx.x;
    const int lane = tid & 63;
    const int wid = tid >> 6;
    const int lo = lane & 15, hi = lane >> 4;
    const int bm = blockIdx.x, bn = blockIdx.y;
    const int wr = wid >> 1, wc = wid & 1;

    const int rowS = (wid * 2) * 16 + (lane >> 2);
    const int colE = (lane & 3) * 8;
    const bf16_t* gA0 = A + (size_t)(bm * 128 + rowS) * Kdim + colE;
    const bf16_t* gA1 = gA0 + (size_t)16 * Kdim;
    const bf16_t* gB0 = Bt + (size_t)(bn * 128 + rowS) * Kdim + colE;
    const bf16_t* gB1 = gB0 + (size_t)16 * Kdim;
    bf16_t* lA0 = &Alds[(wid * 2) * 512];
    bf16_t* lA1 = &Alds[(wid * 2 + 1) * 512];
    bf16_t* lB0 = &Blds[(wid * 2) * 512];
    bf16_t* lB1 = &Blds[(wid * 2 + 1) * 512];

    f32x4 acc[4][4];
#pragma unroll
    for (int m = 0; m < 4; ++m)
#pragma unroll
        for (int n = 0; n < 4; ++n) acc[m][n] = (f32x4){0.f, 0.f, 0.f, 0.f};

    const int nk = Kdim >> 5;
    for (int kt = 0; kt < nk; ++kt) {
        const int k0 = kt * 32;
        GLDS16(gA0 + k0, lA0);
        GLDS16(gA1 + k0, lA1);
        GLDS16(gB0 + k0, lB0);
        GLDS16(gB1 + k0, lB1);
        __syncthreads();
        bf16x8 aF[4], bF[4];
#pragma unroll
        for (int m = 0; m < 4; ++m)
            aF[m] = *(const bf16x8*)&Alds[(wr * 64 + m * 16 + lo) * 32 + hi * 8];
#pragma unroll
        for (int n = 0; n < 4; ++n)
            bF[n] = *(const bf16x8*)&Blds[(wc * 64 + n * 16 + lo) * 32 + hi * 8];
#pragma unroll
        for (int m = 0; m < 4; ++m)
#pragma unroll
            for (int n = 0; n < 4; ++n)
                acc[m][n] = MFMA16(aF[m], bF[n], acc[m][n]);
        __syncthreads();
    }

    const int rbase = bm * 128 + wr * 64 + hi * 4;
    const int cbase = bn * 128 + wc * 64 + lo;
    if (MODE == 0) {
        bf16_t* C = (bf16_t*)Cout;
#pragma unroll
        for (int m = 0; m < 4; ++m)
#pragma unroll
            for (int n = 0; n < 4; ++n) {
                const int col = cbase + n * 16;
                const float bias = (col < 1024) ? b0[col]
                                 : (col < 2048) ? b1[col - 1024] : b2[col - 2048];
#pragma unroll
                for (int r = 0; r < 4; ++r) {
                    const int row = rbase + m * 16 + r;
                    C[(size_t)row * Ndim + col] = (bf16_t)(acc[m][n][r] + bias);
                }
            }
    } else {
        float* C = (float*)Cout;
#pragma unroll
        for (int m = 0; m < 4; ++m)
#pragma unroll
            for (int n = 0; n < 4; ++n) {
                const int col = cbase + n * 16;
                const float bias = b0[col];
#pragma unroll
                for (int r = 0; r < 4; ++r) {
                    const int row = rbase + m * 16 + r;
                    C[(size_t)row * Ndim + col] = acc[m][n][r] + bias;
                }
            }
    }
}

// ---------------------------------------------------------------------------
// K3: fused RoPE(Q,K) + V-transpose (r15-verified)
// ---------------------------------------------------------------------------
__global__ __launch_bounds__(256)
void qkvprep_kernel(const bf16_t* __restrict__ qkv,
                    const float* __restrict__ cosT,
                    const float* __restrict__ sinT,
                    bf16_t* __restrict__ Qr, bf16_t* __restrict__ Kr,
                    bf16_t* __restrict__ VT) {
    const int st = blockIdx.x, bh = blockIdx.y;
    const int b = bh >> 4, h = bh & 15;
    const int tid = threadIdx.x;
    {
        const int r = tid >> 2;
        const int part = tid & 3;
        const int s = st * 64 + r;
        const int bs = b * kS + s;
        const bf16_t* qp = qkv + (size_t)bs * kNqkv + h * 64 + part * 16;
        const bf16_t* kp = qp + 1024;
        const size_t outoff = ((size_t)(b * kH + h) * kS + s) * 64;
        bf16_t* qo = Qr + outoff;
        char*   kob = (char*)(Kr + outoff);
        const float* cr = cosT + s * 32 + part * 8;
        const float* sr = sinT + s * 32 + part * 8;
        const float kScale = 0.125f * 1.44269504f;

        bf16x8 q0 = *(const bf16x8*)qp;
        bf16x8 q1 = *(const bf16x8*)(qp + 8);
        bf16x8 k0 = *(const bf16x8*)kp;
        bf16x8 k1 = *(const bf16x8*)(kp + 8);
        bf16x8 qlo, qhi, klo, khi;
#pragma unroll
        for (int j = 0; j < 8; ++j) {
            const float cv = cr[j];
            const float sv = sr[j];
            float qa, qb2, ka, kb2;
            if (j < 4) {
                qa = (float)q0[2 * j];     qb2 = (float)q0[2 * j + 1];
                ka = (float)k0[2 * j];     kb2 = (float)k0[2 * j + 1];
            } else {
                qa = (float)q1[2 * j - 8]; qb2 = (float)q1[2 * j - 7];
                ka = (float)k1[2 * j - 8]; kb2 = (float)k1[2 * j - 7];
            }
            qlo[j] = (bf16_t)((qa * cv - qb2 * sv) * kScale);
            qhi[j] = (bf16_t)((qa * sv + qb2 * cv) * kScale);
            klo[j] = (bf16_t)(ka * cv - kb2 * sv);
            khi[j] = (bf16_t)(ka * sv + kb2 * cv);
        }
        *(bf16x8*)(qo + part * 8)      = qlo;
        *(bf16x8*)(qo + 32 + part * 8) = qhi;
        const int sw = s & 7;
        *(bf16x8*)(kob + (((part)     ^ sw) << 4)) = klo;
        *(bf16x8*)(kob + (((part + 4) ^ sw) << 4)) = khi;
    }
    {
        __shared__ __align__(16) bf16_t t[64 * 72];
        const int r = tid >> 2, g = tid & 3;
        const bf16_t* src = qkv + ((size_t)(b * kS + st * 64 + r)) * kNqkv + 2048 + h * 64 + g * 16;
        bf16x8 v0 = *(const bf16x8*)src;
        bf16x8 v1 = *(const bf16x8*)(src + 8);
        *(bf16x8*)&t[r * 72 + g * 16] = v0;
        *(bf16x8*)&t[r * 72 + g * 16 + 8] = v1;
        __syncthreads();
        bf16x8 o0, o1;
#pragma unroll
        for (int j = 0; j < 8; ++j) {
            o0[j] = t[(g * 16 + j) * 72 + r];
            o1[j] = t[(g * 16 + 8 + j) * 72 + r];
        }
        char* dstb = (char*)(VT + ((size_t)bh * 64 + r) * kS) + st * 128;
        const int sw = r & 7;
        *(bf16x8*)(dstb + (((g * 2)     ^ sw) << 4)) = o0;
        *(bf16x8*)(dstb + (((g * 2 + 1) ^ sw) << 4)) = o1;
    }
}

// ---------------------------------------------------------------------------
// K5: causal flash attention (r12/r13/r15-verified) — swapped-QK^T scalar
// softmax, XOR-swizzled P, LPT boustrophedon qt remap, dbuf KV staging.
// ---------------------------------------------------------------------------
__global__ __launch_bounds__(256, 4)
void attn_kernel(const bf16_t* __restrict__ Qr, const bf16_t* __restrict__ Kr,
                 const bf16_t* __restrict__ VT, bf16_t* __restrict__ attended) {
    __shared__ __align__(16) bf16_t Klds[2][64 * 64];
    __shared__ __align__(16) bf16_t Vlds[2][64 * 64];
    __shared__ __align__(16) bf16_t Plds[4][16 * 64];
    const int bh = blockIdx.x;
    const int y = blockIdx.y;
    const int qt = (y < 8) ? (31 - y) : (y < 16) ? (y + 8)
                 : (y < 24) ? (31 - y) : (y - 24);
    const int tid = threadIdx.x;
    const int lane = tid & 63, wid = tid >> 6;
    const int lo = lane & 15, hi = lane >> 4;
    const int q0 = qt * 64 + wid * 16;

    const char* Kg = (const char*)(Kr + (size_t)bh * kS * 64);
    const char* Vg = (const char*)(VT + (size_t)bh * 64 * kS);
    const bf16_t* Q = Qr + (size_t)bh * kS * 64;

    const bf16x8 aQ0 = *(const bf16x8*)&Q[(size_t)(q0 + lo) * 64 + hi * 8];
    const bf16x8 aQ1 = *(const bf16x8*)&Q[(size_t)(q0 + lo) * 64 + 32 + hi * 8];

    char* Pb = (char*)&Plds[wid][0];
    const int psw = (lo & 7) << 4;

    f32x4 O[4];
#pragma unroll
    for (int dt = 0; dt < 4; ++dt) O[dt] = (f32x4){0.f, 0.f, 0.f, 0.f};
    float m_run = -1e30f, l_run = 0.f;

    auto stage = [&](int buf, int t) {
        char* Kl = (char*)&Klds[buf][0];
        char* Vl = (char*)&Vlds[buf][0];
        const size_t kb = (size_t)t * 128 * 64;
        const int vcol = t * 128;
#pragma unroll
        for (int j = 0; j < 2; ++j) {
            const int seg = wid * 2 + j;
            GLDS16(Kg + kb + seg * 1024 + lane * 16, Kl + seg * 1024);
            const int row = seg * 8 + (lane >> 3);
            GLDS16(Vg + (size_t)row * (kS * 2) + vcol + (lane & 7) * 16, Vl + seg * 1024);
        }
    };

    stage(0, 0);
    int cur = 0;
    const int ntiles = qt + 1;
    for (int t = 0; t < ntiles; ++t) {
        __syncthreads();
        if (t + 1 < ntiles) stage(cur ^ 1, t + 1);
        const char* Kb = (const char*)&Klds[cur][0];
        const char* Vb = (const char*)&Vlds[cur][0];
        const int kv0 = t * 64;
        const bool edge = (t == qt);

        f32x4 s[4];
#pragma unroll
        for (int ct = 0; ct < 4; ++ct) s[ct] = (f32x4){0.f, 0.f, 0.f, 0.f};
        __builtin_amdgcn_s_setprio(1);
#pragma unroll
        for (int ct = 0; ct < 4; ++ct) {
            const int rr = ct * 16 + lo;
            const bf16x8 bK0 = *(const bf16x8*)(Kb + rr * 128 + (((hi)     ^ (rr & 7)) << 4));
            const bf16x8 bK1 = *(const bf16x8*)(Kb + rr * 128 + (((hi + 4) ^ (rr & 7)) << 4));
            s[ct] = MFMA16(bK0, aQ0, s[ct]);
            s[ct] = MFMA16(bK1, aQ1, s[ct]);
        }
        __builtin_amdgcn_s_setprio(0);

        if (edge) {
            const int qg = q0 + lo;
#pragma unroll
            for (int ct = 0; ct < 4; ++ct)
#pragma unroll
                for (int r = 0; r < 4; ++r)
                    if (kv0 + ct * 16 + hi * 4 + r > qg) s[ct][r] = -1e30f;
        }
        float pmax = -1e30f;
#pragma unroll
        for (int ct = 0; ct < 4; ++ct)
#pragma unroll
            for (int r = 0; r < 4; ++r) pmax = fmaxf(pmax, s[ct][r]);
        pmax = fmaxf(pmax, __shfl_xor(pmax, 16, 64));
        pmax = fmaxf(pmax, __shfl_xor(pmax, 32, 64));
        if (!__all(pmax - m_run <= 8.0f)) {
            const float mn = fmaxf(m_run, pmax);
            const float alpha = exp2f(m_run - mn);
            m_run = mn;
            l_run *= alpha;
            float av[4];
#pragma unroll
            for (int r = 0; r < 4; ++r) av[r] = __shfl(alpha, hi * 4 + r, 64);
#pragma unroll
            for (int dt = 0; dt < 4; ++dt)
#pragma unroll
                for (int r = 0; r < 4; ++r) O[dt][r] *= av[r];
        }
        float psum = 0.f;
#pragma unroll
        for (int ct = 0; ct < 4; ++ct)
#pragma unroll
            for (int r = 0; r < 4; ++r) {
                const float e = exp2f(s[ct][r] - m_run);
                s[ct][r] = e;
                psum += e;
            }
        psum += __shfl_xor(psum, 16, 64);
        psum += __shfl_xor(psum, 32, 64);
        l_run += psum;
#pragma unroll
        for (int ct = 0; ct < 4; ++ct)
#pragma unroll
            for (int rp = 0; rp < 2; ++rp) {
                bf16x2 v;
                v[0] = (bf16_t)s[ct][2 * rp];
                v[1] = (bf16_t)s[ct][2 * rp + 1];
                *(bf16x2*)(Pb + ((lo * 128 + (ct * 16 + hi * 4 + 2 * rp) * 2) ^ psw)) = v;
            }
        const bf16x8 aP0 = *(const bf16x8*)(Pb + ((lo * 128 + hi * 16) ^ psw));
        const bf16x8 aP1 = *(const bf16x8*)(Pb + ((lo * 128 + 64 + hi * 16) ^ psw));

        __builtin_amdgcn_s_setprio(1);
#pragma unroll
        for (int dt = 0; dt < 4; ++dt) {
            const int rr = dt * 16 + lo;
            const bf16x8 bV0 = *(const bf16x8*)(Vb + rr * 128 + (((hi)     ^ (rr & 7)) << 4));
            const bf16x8 bV1 = *(const bf16x8*)(Vb + rr * 128 + (((hi + 4) ^ (rr & 7)) << 4));
            O[dt] = MFMA16(aP0, bV0, O[dt]);
            O[dt] = MFMA16(aP1, bV1, O[dt]);
        }
        __builtin_amdgcn_s_setprio(0);
        cur ^= 1;
    }

    const int b = bh >> 4, h = bh & 15;
    float li[4];
#pragma unroll
    for (int r = 0; r < 4; ++r) li[r] = 1.0f / __shfl(l_run, hi * 4 + r, 64);
#pragma unroll
    for (int dt = 0; dt < 4; ++dt)
#pragma unroll
        for (int r = 0; r < 4; ++r) {
            const int row = q0 + hi * 4 + r;
            attended[((size_t)(b * kS + row)) * kD + h * 64 + dt * 16 + lo] =
                (bf16_t)(O[dt][r] * li[r]);
        }
}

// ---------------------------------------------------------------------------
extern "C" void kernel_launch(void* const* d_in, const int* in_sizes, int n_in,
                              void* d_out, int out_size, void* d_ws, size_t ws_size,
                              hipStream_t stream) {
    const float* x  = (const float*)d_in[0];
    const float* Wq = (const float*)d_in[1];
    const float* bq = (const float*)d_in[2];
    const float* Wk = (const float*)d_in[3];
    const float* bk = (const float*)d_in[4];
    const float* Wv = (const float*)d_in[5];
    const float* bv = (const float*)d_in[6];
    const float* Wo = (const float*)d_in[7];
    const float* bo = (const float*)d_in[8];
    float* out = (float*)d_out;

    char* ws = (char*)d_ws;
    size_t off = 0;
    auto carve = [&](size_t bytes) -> char* {
        char* p = ws + off;
        off += (bytes + 255) & ~(size_t)255;
        return p;
    };
    bf16_t* xb    = (bf16_t*)carve((size_t)kM * kD * 2);
    bf16_t* WqkvT = (bf16_t*)carve((size_t)kNqkv * kD * 2);
    bf16_t* WoT   = (bf16_t*)carve((size_t)kD * kD * 2);
    float*  cosT  = (float*)carve((size_t)kS * 32 * 4);
    float*  sinT  = (float*)carve((size_t)kS * 32 * 4);
    bf16_t* qkv   = (bf16_t*)carve((size_t)kM * kNqkv * 2);
    bf16_t* Qr    = (bf16_t*)carve((size_t)kBH * kS * 64 * 2);
    bf16_t* Kr    = (bf16_t*)carve((size_t)kBH * kS * 64 * 2);
    bf16_t* VT    = (bf16_t*)carve((size_t)kBH * kS * 64 * 2);
    bf16_t* att   = (bf16_t*)carve((size_t)kM * kD * 2);

    prep_kernel<<<8448, 256, 0, stream>>>(x, xb, Wq, Wk, Wv, Wo, WqkvT, WoT, cosT, sinT);

    gemm_bf16<0><<<dim3(kM / 128, kNqkv / 128), 256, 0, stream>>>(
        xb, WqkvT, qkv, bq, bk, bv, kNqkv, kD);

    qkvprep_kernel<<<dim3(kS / 64, kBH), 256, 0, stream>>>(qkv, cosT, sinT, Qr, Kr, VT);

    attn_kernel<<<dim3(kBH, 32), 256, 0, stream>>>(Qr, Kr, VT, att);

    gemm_bf16<1><<<dim3(kM / 128, kD / 128), 256, 0, stream>>>(
        att, WoT, out, bo, nullptr, nullptr, kD, kD);
}

// Round 19
// 121.036 us; speedup vs baseline: 1.0748x; 1.0391x over previous
//
#include <hip/hip_runtime.h>
#include <hip/hip_bf16.h>

typedef __bf16 bf16_t;
typedef __bf16 bf16x2 __attribute__((ext_vector_type(2)));
typedef __bf16 bf16x4 __attribute__((ext_vector_type(4)));
typedef __bf16 bf16x8 __attribute__((ext_vector_type(8)));
typedef float  f32x4  __attribute__((ext_vector_type(4)));

#define GLDS16(gp, lp) __builtin_amdgcn_global_load_lds( \
    (const __attribute__((address_space(1))) void*)(gp), \
    (__attribute__((address_space(3))) void*)(lp), 16, 0, 0)

#define MFMA16(a, b, c) __builtin_amdgcn_mfma_f32_16x16x32_bf16((a), (b), (c), 0, 0, 0)

static constexpr int kB = 2, kS = 2048, kD = 1024, kH = 16, kL = 64;
static constexpr int kM = kB * kS;       // 4096 rows
static constexpr int kNqkv = 3 * kD;     // 3072
static constexpr int kBH = kB * kH;      // 32

// ---------------------------------------------------------------------------
// K1: fused prep — blockIdx.x ranges: [0,4096) cast_x; [4096,8192) wtrans;
// [8192,8448) rope_table.
// ---------------------------------------------------------------------------
__global__ __launch_bounds__(256)
void prep_kernel(const float* __restrict__ x, bf16_t* __restrict__ xb,
                 const float* __restrict__ Wq, const float* __restrict__ Wk,
                 const float* __restrict__ Wv, const float* __restrict__ Wo,
                 bf16_t* __restrict__ Wqkv, bf16_t* __restrict__ WoT,
                 float* __restrict__ cosT, float* __restrict__ sinT) {
    const int bid = blockIdx.x;
    const int tid = threadIdx.x;
    if (bid < 4096) {
        int i = bid * 256 + tid;
        float4 v = ((const float4*)x)[i];
        bf16x4 o;
        o[0] = (bf16_t)v.x; o[1] = (bf16_t)v.y; o[2] = (bf16_t)v.z; o[3] = (bf16_t)v.w;
        ((bf16x4*)xb)[i] = o;
    } else if (bid < 8192) {
        __shared__ float t[32 * 33];
        const int wid4 = bid - 4096;
        const int z = wid4 >> 10;
        const int rem = wid4 & 1023;
        const int k0 = (rem & 31) * 32, n0 = (rem >> 5) * 32;
        const float* W = (z == 0) ? Wq : (z == 1) ? Wk : (z == 2) ? Wv : Wo;
        bf16_t* Wt = (z < 3) ? (Wqkv + (size_t)z * 1024 * 1024) : WoT;
#pragma unroll
        for (int i = 0; i < 4; ++i) {
            int idx = i * 256 + tid;
            int r = idx >> 5, c = idx & 31;
            t[r * 33 + c] = W[(size_t)(k0 + r) * 1024 + n0 + c];
        }
        __syncthreads();
#pragma unroll
        for (int i = 0; i < 4; ++i) {
            int idx = i * 256 + tid;
            int r = idx >> 5, c = idx & 31;
            Wt[(size_t)(n0 + r) * 1024 + k0 + c] = (bf16_t)t[c * 33 + r];
        }
    } else {
        int i = (bid - 8192) * 256 + tid;
        int s = i >> 5, j = i & 31;
        double inv = pow(10000.0, -2.0 * (double)j / 64.0);
        double ang = (double)s * inv;
        cosT[i] = (float)cos(ang);
        sinT[i] = (float)sin(ang);
    }
}

// ---------------------------------------------------------------------------
// K2/K8: bf16 GEMM — BK=64 (half the barriers), source-permuted staging +
// XOR'd fragment reads (attn-verified involution; LDS stays linear for
// global_load_lds). Chunk = 8 rows x 128B; perm = (lane&7)^(row&7);
// frag read chunk = k_chunk ^ (lo&7). 32KB LDS, 2 blocks/CU.
// ---------------------------------------------------------------------------
template <int MODE>
__global__ __launch_bounds__(256, 2)
void gemm_bf16(const bf16_t* __restrict__ A, const bf16_t* __restrict__ Bt,
               void* __restrict__ Cout,
               const float* __restrict__ b0, const float* __restrict__ b1,
               const float* __restrict__ b2, int Ndim, int Kdim) {
    __shared__ __align__(16) bf16_t Alds[128 * 64];
    __shared__ __align__(16) bf16_t Blds[128 * 64];
    const int tid = threadIdx.x;
    const int lane = tid & 63;
    const int wid = tid >> 6;
    const int lo = lane & 15, hi = lane >> 4;
    const int bm = blockIdx.x, bn = blockIdx.y;
    const int wr = wid >> 1, wc = wid & 1;

    // staging geometry: 16 chunks of 1KB per matrix; chunk = 8 rows x 64 cols.
    // lane: row-in-chunk = lane>>3, permuted 16B col-chunk = (lane&7)^(rowL&7)
    const int rowL = lane >> 3;
    const int colP = (lane & 7) ^ rowL;       // rowL in 0..7
    const int asw = lo & 7;                   // fragment-read swizzle mask

    f32x4 acc[4][4];
#pragma unroll
    for (int m = 0; m < 4; ++m)
#pragma unroll
        for (int n = 0; n < 4; ++n) acc[m][n] = (f32x4){0.f, 0.f, 0.f, 0.f};

    auto stage = [&](int kt) {
        const int k0 = kt * 64;
#pragma unroll
        for (int j = 0; j < 4; ++j) {
            const int seg = wid * 4 + j;
            const int row = seg * 8 + rowL;
            GLDS16(A  + (size_t)(bm * 128 + row) * Kdim + k0 + colP * 8,
                   &Alds[seg * 512 + lane * 8]);
            GLDS16(Bt + (size_t)(bn * 128 + row) * Kdim + k0 + colP * 8,
                   &Blds[seg * 512 + lane * 8]);
        }
    };

    const int nk = Kdim >> 6;
    for (int kt = 0; kt < nk; ++kt) {
        stage(kt);
        __syncthreads();
        bf16x8 aF0[4], aF1[4], bF0[4], bF1[4];
#pragma unroll
        for (int m = 0; m < 4; ++m) {
            const int R = wr * 64 + m * 16 + lo;
            aF0[m] = *(const bf16x8*)&Alds[R * 64 + ((hi ^ asw) * 8)];
            aF1[m] = *(const bf16x8*)&Alds[R * 64 + (((hi + 4) ^ asw) * 8)];
        }
#pragma unroll
        for (int n = 0; n < 4; ++n) {
            const int R = wc * 64 + n * 16 + lo;
            bF0[n] = *(const bf16x8*)&Blds[R * 64 + ((hi ^ asw) * 8)];
            bF1[n] = *(const bf16x8*)&Blds[R * 64 + (((hi + 4) ^ asw) * 8)];
        }
#pragma unroll
        for (int m = 0; m < 4; ++m)
#pragma unroll
            for (int n = 0; n < 4; ++n) {
                acc[m][n] = MFMA16(aF0[m], bF0[n], acc[m][n]);
                acc[m][n] = MFMA16(aF1[m], bF1[n], acc[m][n]);
            }
        __syncthreads();
    }

    const int rbase = bm * 128 + wr * 64 + hi * 4;
    const int cbase = bn * 128 + wc * 64 + lo;
    if (MODE == 0) {
        bf16_t* C = (bf16_t*)Cout;
#pragma unroll
        for (int m = 0; m < 4; ++m)
#pragma unroll
            for (int n = 0; n < 4; ++n) {
                const int col = cbase + n * 16;
                const float bias = (col < 1024) ? b0[col]
                                 : (col < 2048) ? b1[col - 1024] : b2[col - 2048];
#pragma unroll
                for (int r = 0; r < 4; ++r) {
                    const int row = rbase + m * 16 + r;
                    C[(size_t)row * Ndim + col] = (bf16_t)(acc[m][n][r] + bias);
                }
            }
    } else {
        float* C = (float*)Cout;
#pragma unroll
        for (int m = 0; m < 4; ++m)
#pragma unroll
            for (int n = 0; n < 4; ++n) {
                const int col = cbase + n * 16;
                const float bias = b0[col];
#pragma unroll
                for (int r = 0; r < 4; ++r) {
                    const int row = rbase + m * 16 + r;
                    C[(size_t)row * Ndim + col] = acc[m][n][r] + bias;
                }
            }
    }
}

// ---------------------------------------------------------------------------
// K3: fused RoPE(Q,K) + V-transpose (r15-verified)
// ---------------------------------------------------------------------------
__global__ __launch_bounds__(256)
void qkvprep_kernel(const bf16_t* __restrict__ qkv,
                    const float* __restrict__ cosT,
                    const float* __restrict__ sinT,
                    bf16_t* __restrict__ Qr, bf16_t* __restrict__ Kr,
                    bf16_t* __restrict__ VT) {
    const int st = blockIdx.x, bh = blockIdx.y;
    const int b = bh >> 4, h = bh & 15;
    const int tid = threadIdx.x;
    {
        const int r = tid >> 2;
        const int part = tid & 3;
        const int s = st * 64 + r;
        const int bs = b * kS + s;
        const bf16_t* qp = qkv + (size_t)bs * kNqkv + h * 64 + part * 16;
        const bf16_t* kp = qp + 1024;
        const size_t outoff = ((size_t)(b * kH + h) * kS + s) * 64;
        bf16_t* qo = Qr + outoff;
        char*   kob = (char*)(Kr + outoff);
        const float* cr = cosT + s * 32 + part * 8;
        const float* sr = sinT + s * 32 + part * 8;
        const float kScale = 0.125f * 1.44269504f;

        bf16x8 q0 = *(const bf16x8*)qp;
        bf16x8 q1 = *(const bf16x8*)(qp + 8);
        bf16x8 k0 = *(const bf16x8*)kp;
        bf16x8 k1 = *(const bf16x8*)(kp + 8);
        bf16x8 qlo, qhi, klo, khi;
#pragma unroll
        for (int j = 0; j < 8; ++j) {
            const float cv = cr[j];
            const float sv = sr[j];
            float qa, qb2, ka, kb2;
            if (j < 4) {
                qa = (float)q0[2 * j];     qb2 = (float)q0[2 * j + 1];
                ka = (float)k0[2 * j];     kb2 = (float)k0[2 * j + 1];
            } else {
                qa = (float)q1[2 * j - 8]; qb2 = (float)q1[2 * j - 7];
                ka = (float)k1[2 * j - 8]; kb2 = (float)k1[2 * j - 7];
            }
            qlo[j] = (bf16_t)((qa * cv - qb2 * sv) * kScale);
            qhi[j] = (bf16_t)((qa * sv + qb2 * cv) * kScale);
            klo[j] = (bf16_t)(ka * cv - kb2 * sv);
            khi[j] = (bf16_t)(ka * sv + kb2 * cv);
        }
        *(bf16x8*)(qo + part * 8)      = qlo;
        *(bf16x8*)(qo + 32 + part * 8) = qhi;
        const int sw = s & 7;
        *(bf16x8*)(kob + (((part)     ^ sw) << 4)) = klo;
        *(bf16x8*)(kob + (((part + 4) ^ sw) << 4)) = khi;
    }
    {
        __shared__ __align__(16) bf16_t t[64 * 72];
        const int r = tid >> 2, g = tid & 3;
        const bf16_t* src = qkv + ((size_t)(b * kS + st * 64 + r)) * kNqkv + 2048 + h * 64 + g * 16;
        bf16x8 v0 = *(const bf16x8*)src;
        bf16x8 v1 = *(const bf16x8*)(src + 8);
        *(bf16x8*)&t[r * 72 + g * 16] = v0;
        *(bf16x8*)&t[r * 72 + g * 16 + 8] = v1;
        __syncthreads();
        bf16x8 o0, o1;
#pragma unroll
        for (int j = 0; j < 8; ++j) {
            o0[j] = t[(g * 16 + j) * 72 + r];
            o1[j] = t[(g * 16 + 8 + j) * 72 + r];
        }
        char* dstb = (char*)(VT + ((size_t)bh * 64 + r) * kS) + st * 128;
        const int sw = r & 7;
        *(bf16x8*)(dstb + (((g * 2)     ^ sw) << 4)) = o0;
        *(bf16x8*)(dstb + (((g * 2 + 1) ^ sw) << 4)) = o1;
    }
}

// ---------------------------------------------------------------------------
// K5: causal flash attention (r12/r13/r15-verified)
// ---------------------------------------------------------------------------
__global__ __launch_bounds__(256, 4)
void attn_kernel(const bf16_t* __restrict__ Qr, const bf16_t* __restrict__ Kr,
                 const bf16_t* __restrict__ VT, bf16_t* __restrict__ attended) {
    __shared__ __align__(16) bf16_t Klds[2][64 * 64];
    __shared__ __align__(16) bf16_t Vlds[2][64 * 64];
    __shared__ __align__(16) bf16_t Plds[4][16 * 64];
    const int bh = blockIdx.x;
    const int y = blockIdx.y;
    const int qt = (y < 8) ? (31 - y) : (y < 16) ? (y + 8)
                 : (y < 24) ? (31 - y) : (y - 24);
    const int tid = threadIdx.x;
    const int lane = tid & 63, wid = tid >> 6;
    const int lo = lane & 15, hi = lane >> 4;
    const int q0 = qt * 64 + wid * 16;

    const char* Kg = (const char*)(Kr + (size_t)bh * kS * 64);
    const char* Vg = (const char*)(VT + (size_t)bh * 64 * kS);
    const bf16_t* Q = Qr + (size_t)bh * kS * 64;

    const bf16x8 aQ0 = *(const bf16x8*)&Q[(size_t)(q0 + lo) * 64 + hi * 8];
    const bf16x8 aQ1 = *(const bf16x8*)&Q[(size_t)(q0 + lo) * 64 + 32 + hi * 8];

    char* Pb = (char*)&Plds[wid][0];
    const int psw = (lo & 7) << 4;

    f32x4 O[4];
#pragma unroll
    for (int dt = 0; dt < 4; ++dt) O[dt] = (f32x4){0.f, 0.f, 0.f, 0.f};
    float m_run = -1e30f, l_run = 0.f;

    auto stage = [&](int buf, int t) {
        char* Kl = (char*)&Klds[buf][0];
        char* Vl = (char*)&Vlds[buf][0];
        const size_t kb = (size_t)t * 128 * 64;
        const int vcol = t * 128;
#pragma unroll
        for (int j = 0; j < 2; ++j) {
            const int seg = wid * 2 + j;
            GLDS16(Kg + kb + seg * 1024 + lane * 16, Kl + seg * 1024);
            const int row = seg * 8 + (lane >> 3);
            GLDS16(Vg + (size_t)row * (kS * 2) + vcol + (lane & 7) * 16, Vl + seg * 1024);
        }
    };

    stage(0, 0);
    int cur = 0;
    const int ntiles = qt + 1;
    for (int t = 0; t < ntiles; ++t) {
        __syncthreads();
        if (t + 1 < ntiles) stage(cur ^ 1, t + 1);
        const char* Kb = (const char*)&Klds[cur][0];
        const char* Vb = (const char*)&Vlds[cur][0];
        const int kv0 = t * 64;
        const bool edge = (t == qt);

        f32x4 s[4];
#pragma unroll
        for (int ct = 0; ct < 4; ++ct) s[ct] = (f32x4){0.f, 0.f, 0.f, 0.f};
        __builtin_amdgcn_s_setprio(1);
#pragma unroll
        for (int ct = 0; ct < 4; ++ct) {
            const int rr = ct * 16 + lo;
            const bf16x8 bK0 = *(const bf16x8*)(Kb + rr * 128 + (((hi)     ^ (rr & 7)) << 4));
            const bf16x8 bK1 = *(const bf16x8*)(Kb + rr * 128 + (((hi + 4) ^ (rr & 7)) << 4));
            s[ct] = MFMA16(bK0, aQ0, s[ct]);
            s[ct] = MFMA16(bK1, aQ1, s[ct]);
        }
        __builtin_amdgcn_s_setprio(0);

        if (edge) {
            const int qg = q0 + lo;
#pragma unroll
            for (int ct = 0; ct < 4; ++ct)
#pragma unroll
                for (int r = 0; r < 4; ++r)
                    if (kv0 + ct * 16 + hi * 4 + r > qg) s[ct][r] = -1e30f;
        }
        float pmax = -1e30f;
#pragma unroll
        for (int ct = 0; ct < 4; ++ct)
#pragma unroll
            for (int r = 0; r < 4; ++r) pmax = fmaxf(pmax, s[ct][r]);
        pmax = fmaxf(pmax, __shfl_xor(pmax, 16, 64));
        pmax = fmaxf(pmax, __shfl_xor(pmax, 32, 64));
        if (!__all(pmax - m_run <= 8.0f)) {
            const float mn = fmaxf(m_run, pmax);
            const float alpha = exp2f(m_run - mn);
            m_run = mn;
            l_run *= alpha;
            float av[4];
#pragma unroll
            for (int r = 0; r < 4; ++r) av[r] = __shfl(alpha, hi * 4 + r, 64);
#pragma unroll
            for (int dt = 0; dt < 4; ++dt)
#pragma unroll
                for (int r = 0; r < 4; ++r) O[dt][r] *= av[r];
        }
        float psum = 0.f;
#pragma unroll
        for (int ct = 0; ct < 4; ++ct)
#pragma unroll
            for (int r = 0; r < 4; ++r) {
                const float e = exp2f(s[ct][r] - m_run);
                s[ct][r] = e;
                psum += e;
            }
        psum += __shfl_xor(psum, 16, 64);
        psum += __shfl_xor(psum, 32, 64);
        l_run += psum;
#pragma unroll
        for (int ct = 0; ct < 4; ++ct)
#pragma unroll
            for (int rp = 0; rp < 2; ++rp) {
                bf16x2 v;
                v[0] = (bf16_t)s[ct][2 * rp];
                v[1] = (bf16_t)s[ct][2 * rp + 1];
                *(bf16x2*)(Pb + ((lo * 128 + (ct * 16 + hi * 4 + 2 * rp) * 2) ^ psw)) = v;
            }
        const bf16x8 aP0 = *(const bf16x8*)(Pb + ((lo * 128 + hi * 16) ^ psw));
        const bf16x8 aP1 = *(const bf16x8*)(Pb + ((lo * 128 + 64 + hi * 16) ^ psw));

        __builtin_amdgcn_s_setprio(1);
#pragma unroll
        for (int dt = 0; dt < 4; ++dt) {
            const int rr = dt * 16 + lo;
            const bf16x8 bV0 = *(const bf16x8*)(Vb + rr * 128 + (((hi)     ^ (rr & 7)) << 4));
            const bf16x8 bV1 = *(const bf16x8*)(Vb + rr * 128 + (((hi + 4) ^ (rr & 7)) << 4));
            O[dt] = MFMA16(aP0, bV0, O[dt]);
            O[dt] = MFMA16(aP1, bV1, O[dt]);
        }
        __builtin_amdgcn_s_setprio(0);
        cur ^= 1;
    }

    const int b = bh >> 4, h = bh & 15;
    float li[4];
#pragma unroll
    for (int r = 0; r < 4; ++r) li[r] = 1.0f / __shfl(l_run, hi * 4 + r, 64);
#pragma unroll
    for (int dt = 0; dt < 4; ++dt)
#pragma unroll
        for (int r = 0; r < 4; ++r) {
            const int row = q0 + hi * 4 + r;
            attended[((size_t)(b * kS + row)) * kD + h * 64 + dt * 16 + lo] =
                (bf16_t)(O[dt][r] * li[r]);
        }
}

// ---------------------------------------------------------------------------
extern "C" void kernel_launch(void* const* d_in, const int* in_sizes, int n_in,
                              void* d_out, int out_size, void* d_ws, size_t ws_size,
                              hipStream_t stream) {
    const float* x  = (const float*)d_in[0];
    const float* Wq = (const float*)d_in[1];
    const float* bq = (const float*)d_in[2];
    const float* Wk = (const float*)d_in[3];
    const float* bk = (const float*)d_in[4];
    const float* Wv = (const float*)d_in[5];
    const float* bv = (const float*)d_in[6];
    const float* Wo = (const float*)d_in[7];
    const float* bo = (const float*)d_in[8];
    float* out = (float*)d_out;

    char* ws = (char*)d_ws;
    size_t off = 0;
    auto carve = [&](size_t bytes) -> char* {
        char* p = ws + off;
        off += (bytes + 255) & ~(size_t)255;
        return p;
    };
    bf16_t* xb    = (bf16_t*)carve((size_t)kM * kD * 2);
    bf16_t* WqkvT = (bf16_t*)carve((size_t)kNqkv * kD * 2);
    bf16_t* WoT   = (bf16_t*)carve((size_t)kD * kD * 2);
    float*  cosT  = (float*)carve((size_t)kS * 32 * 4);
    float*  sinT  = (float*)carve((size_t)kS * 32 * 4);
    bf16_t* qkv   = (bf16_t*)carve((size_t)kM * kNqkv * 2);
    bf16_t* Qr    = (bf16_t*)carve((size_t)kBH * kS * 64 * 2);
    bf16_t* Kr    = (bf16_t*)carve((size_t)kBH * kS * 64 * 2);
    bf16_t* VT    = (bf16_t*)carve((size_t)kBH * kS * 64 * 2);
    bf16_t* att   = (bf16_t*)carve((size_t)kM * kD * 2);

    prep_kernel<<<8448, 256, 0, stream>>>(x, xb, Wq, Wk, Wv, Wo, WqkvT, WoT, cosT, sinT);

    gemm_bf16<0><<<dim3(kM / 128, kNqkv / 128), 256, 0, stream>>>(
        xb, WqkvT, qkv, bq, bk, bv, kNqkv, kD);

    qkvprep_kernel<<<dim3(kS / 64, kBH), 256, 0, stream>>>(qkv, cosT, sinT, Qr, Kr, VT);

    attn_kernel<<<dim3(kBH, 32), 256, 0, stream>>>(Qr, Kr, VT, att);

    gemm_bf16<1><<<dim3(kM / 128, kD / 128), 256, 0, stream>>>(
        att, WoT, out, bo, nullptr, nullptr, kD, kD);
}